// Round 4
// baseline (450.837 us; speedup 1.0000x reference)
//
#include <hip/hip_runtime.h>
#include <math.h>

typedef unsigned short u16;
typedef unsigned int u32;
typedef __attribute__((ext_vector_type(8))) short short8;   // 8 bf16 (4 VGPRs)
typedef __attribute__((ext_vector_type(4))) float f32x4;

#define DIM 384
#define HID 1536

static __device__ __forceinline__ float bf2f(u32 b){ return __uint_as_float(b << 16); }
static __device__ __forceinline__ u16 f2bf(float f){
  u32 u = __float_as_uint(f);
  u32 r = (u + 0x7fffu + ((u >> 16) & 1u)) >> 16;
  return (u16)r;
}
// tanh-form GELU via sigmoid; |err| ~1e-4 in our operating range
static __device__ __forceinline__ float gelu_fast(float v){
  float u = v * fmaf(0.0713548162726f, v * v, 1.59576912161f);
  float e = __builtin_amdgcn_exp2f(-1.44269504089f * u);
  return v * __builtin_amdgcn_rcpf(1.0f + e);
}
// async global->LDS, 16B/lane; LDS dest = wave-uniform base + lane*16
static __device__ __forceinline__ void gload_lds16(const u16* g, u16* l){
  __builtin_amdgcn_global_load_lds(
      (__attribute__((address_space(1))) void*)(void*)const_cast<u16*>(g),
      (__attribute__((address_space(3))) void*)(void*)l, 16, 0, 0);
}
// counted vmcnt wait (T4: never drain to 0 in the main loop)
template<int N> static __device__ __forceinline__ void vm_wait(){
  if constexpr (N == 0)      asm volatile("s_waitcnt vmcnt(0)" ::: "memory");
  else if constexpr (N == 4) asm volatile("s_waitcnt vmcnt(4)" ::: "memory");
  else if constexpr (N == 5) asm volatile("s_waitcnt vmcnt(5)" ::: "memory");
  else if constexpr (N == 6) asm volatile("s_waitcnt vmcnt(6)" ::: "memory");
  else                       asm volatile("s_waitcnt vmcnt(0)" ::: "memory");
}
static __device__ __forceinline__ void barrier_raw(){
  asm volatile("s_barrier" ::: "memory");
}
static __device__ __forceinline__ void lgkm_wait0(){
  asm volatile("s_waitcnt lgkmcnt(0)" ::: "memory");
}

// ---------------- LayerNorm: f32 in, bf16 out ------------------------------
__global__ __launch_bounds__(256) void ln_kernel(const float* __restrict__ x,
    const float* __restrict__ sc, const float* __restrict__ bi, u16* __restrict__ y){
  int lane = threadIdx.x & 63;
  int row = blockIdx.x * 4 + (threadIdx.x >> 6);
  const float* xr = x + (size_t)row * DIM;
  float v[6];
  float s = 0.f, sq = 0.f;
#pragma unroll
  for (int i = 0; i < 6; ++i){
    float f = xr[lane + 64*i];
    v[i] = f; s += f; sq += f*f;
  }
#pragma unroll
  for (int o = 1; o < 64; o <<= 1){ s += __shfl_xor(s, o); sq += __shfl_xor(sq, o); }
  float mean = s * (1.0f/DIM);
  float var = sq * (1.0f/DIM) - mean*mean;
  float inv = rsqrtf(var + 1e-5f);
  u16* yr = y + (size_t)row * DIM;
#pragma unroll
  for (int i = 0; i < 6; ++i){
    int c = lane + 64*i;
    yr[c] = f2bf((v[i] - mean) * inv * sc[c] + bi[c]);
  }
}

// ---------------- 3D RoPE, in-place on q (bf16) ----------------------------
__global__ __launch_bounds__(256) void rope_kernel(u16* __restrict__ q,
    const int* __restrict__ Tp, const int* __restrict__ Hp, const int* __restrict__ Wp,
    int Mtok){
  int idx = blockIdx.x * 256 + threadIdx.x;   // one thread per rotated pair
  int tok = idx / 192;                         // 192 pairs per token
  if (tok >= Mtok) return;
  int p = idx - tok * 192;
  int H = *Hp, W = *Wp, T = *Tp;
  int HW = H * W;
  int Ns = T * HW;
  int n = tok % Ns;
  int head = p / 12;
  int pp = p - head * 12;
  int s = pp >> 2, f = pp & 3;
  float pos;
  if (s == 0)      pos = (float)(n / HW);
  else if (s == 1) pos = (float)((n / W) % H);
  else             pos = (float)(n % W);
  const float LOG2_10000 = 13.28771237954945f;
  float inv = __builtin_amdgcn_exp2f(-0.25f * (float)f * LOG2_10000);
  float ang = pos * inv;
  float sn = __sinf(ang), cs = __cosf(ang);
  size_t base = (size_t)tok * DIM + head * 24 + s * 8 + 2 * f;
  u32 u = *(u32*)(q + base);
  float x1 = bf2f(u & 0xffffu), x2 = bf2f(u >> 16);
  float y1 = x1 * cs - x2 * sn;
  float y2 = x1 * sn + x2 * cs;
  *(u32*)(q + base) = (u32)f2bf(y1) | ((u32)f2bf(y2) << 16);
}

// -------- weight transpose+convert: f32 in[R][C] -> bf16 out[C][R'] --------
template<int R, int C>
__global__ __launch_bounds__(256) void transpose_kernel(
    const float* __restrict__ s0, const float* __restrict__ s1,
    const float* __restrict__ s2, const float* __restrict__ s3,
    u16* __restrict__ d0, u16* __restrict__ d1, u16* __restrict__ d2, u16* __restrict__ d3,
    int dstStride){
  const float* src = (blockIdx.z == 0) ? s0 : (blockIdx.z == 1) ? s1 : (blockIdx.z == 2) ? s2 : s3;
  u16* dst         = (blockIdx.z == 0) ? d0 : (blockIdx.z == 1) ? d1 : (blockIdx.z == 2) ? d2 : d3;
  __shared__ u16 t[32][33];
  int tx = threadIdx.x & 31, ty = threadIdx.x >> 5;  // 32 x 8
  int r0 = blockIdx.y * 32, c0 = blockIdx.x * 32;
#pragma unroll
  for (int i = 0; i < 4; ++i)
    t[ty + 8*i][tx] = f2bf(src[(size_t)(r0 + ty + 8*i) * C + c0 + tx]);
  __syncthreads();
#pragma unroll
  for (int i = 0; i < 4; ++i)
    dst[(size_t)(c0 + ty + 8*i) * dstStride + r0 + tx] = t[tx][ty + 8*i];
}

// ---------------- sum 3 bias vectors of 384 --------------------------------
__global__ void bias3_kernel(const float* __restrict__ b, float* __restrict__ o){
  int n = threadIdx.x;
  o[n] = b[n] + b[384 + n] + b[768 + n];
}

// ---------------- MFMA GEMM: C = A[M,K] @ Bt[N,K]^T ------------------------
enum { E_NONE = 0, E_BIAS = 1, E_RES_F32 = 3, E_FINAL = 5 };

template<int BM, int N, int K, int EPI>
__global__ __launch_bounds__(256) void gemm_kernel(
    const u16* __restrict__ A, const u16* __restrict__ Bt,
    void* __restrict__ Cv, const float* __restrict__ bias,
    const float* __restrict__ res, float* __restrict__ accbuf){
  constexpr int BN = 128, BK = 64;
  constexpr int MT = BM / 32, NT = 4;
  constexpr int AIT = BM / 32, BIT = 4;
  __shared__ __align__(16) u16 As[BM * BK];
  __shared__ __align__(16) u16 Bs[BN * BK];
  const int tid = threadIdx.x;
  const int lane = tid & 63;
  const int wv = tid >> 6;
  const int wm = (wv >> 1) * (BM / 2);
  const int wn = (wv & 1) * 64;
  const int quad = lane >> 4;
  const int l16 = lane & 15;
  const int rsw = l16 & 7;
  const size_t m0 = (size_t)blockIdx.x * BM;
  const int n0 = blockIdx.y * BN;
  const int srow = lane >> 3;
  const int scol = ((lane & 7) ^ srow) * 8;

  f32x4 acc[MT][NT];
  const f32x4 zero = {0.f, 0.f, 0.f, 0.f};
#pragma unroll
  for (int mt = 0; mt < MT; ++mt)
#pragma unroll
    for (int nt = 0; nt < NT; ++nt) acc[mt][nt] = zero;

  for (int kt = 0; kt < K; kt += BK){
#pragma unroll
    for (int i = 0; i < AIT; ++i){
      int seg = i * 4 + wv;
      gload_lds16(A + (m0 + (size_t)(seg * 8 + srow)) * K + kt + scol, As + seg * 512);
    }
#pragma unroll
    for (int i = 0; i < BIT; ++i){
      int seg = i * 4 + wv;
      gload_lds16(Bt + (size_t)(n0 + seg * 8 + srow) * K + kt + scol, Bs + seg * 512);
    }
    __syncthreads();
#pragma unroll
    for (int kk = 0; kk < 2; ++kk){
      short8 af[MT], bfr[NT];
#pragma unroll
      for (int mt = 0; mt < MT; ++mt)
        af[mt] = *(const short8*)(As + (wm + mt*16 + l16) * BK + (((kk*4 + quad) ^ rsw) << 3));
#pragma unroll
      for (int nt = 0; nt < NT; ++nt)
        bfr[nt] = *(const short8*)(Bs + (wn + nt*16 + l16) * BK + (((kk*4 + quad) ^ rsw) << 3));
#pragma unroll
      for (int mt = 0; mt < MT; ++mt)
#pragma unroll
        for (int nt = 0; nt < NT; ++nt)
          acc[mt][nt] = __builtin_amdgcn_mfma_f32_16x16x32_bf16(af[mt], bfr[nt], acc[mt][nt], 0, 0, 0);
    }
    __syncthreads();
  }

  // epilogue: C/D mapping col = lane&15, row = quad*4 + reg  [m89-verified]
#pragma unroll
  for (int mt = 0; mt < MT; ++mt){
#pragma unroll
    for (int nt = 0; nt < NT; ++nt){
      int ncol = n0 + wn + nt*16 + l16;
      float bv = (EPI != E_NONE) ? bias[ncol] : 0.f;
      size_t mbase = m0 + wm + mt*16 + quad*4;
#pragma unroll
      for (int r = 0; r < 4; ++r){
        size_t off = (mbase + r) * N + ncol;
        float vv = acc[mt][nt][r];
        if      (EPI == E_NONE)      ((u16*)Cv)[off] = f2bf(vv);
        else if (EPI == E_BIAS)      ((u16*)Cv)[off] = f2bf(vv + bv);
        else /* E_RES_F32 */         accbuf[off] = vv + bv + res[off];
      }
    }
  }
}

// ---------------- Fused MLP v4: C = gelu(A @ W1t^T + b1) @ W2t^T (+b2) -----
// Changes vs v3, driven by LDS-traffic accounting (v3 was LDS-bound):
//  * A[64][384] staged ONCE per block (48 KB resident; R2-verified math) --
//    removes per-chunk A re-staging, up-tiles stage W1 panel only (ring 2x32K).
//  * W2 fragments loaded global->register DIRECTLY (each wave reads a
//    DISJOINT 48-row W2 slice => LDS sharing is worthless; removes 392 KB
//    LDS/chunk + all down-phase staging), with a named 2-deep register
//    double-buffer (static indices) so L2 latency hides under MFMA.
//  * Down phase is barrier-free (af from Hs, bfr from global).
// LDS 48+64+32 = 144 KB, 1 block/CU, 8 waves. Up-tiles stay on the v3
// counted-vmcnt ring (4 loads/tile -> vm_wait<4>).
template<int HIDT, int NCH, int EPI>
__global__ __launch_bounds__(512, 2) void fused_mlp4_kernel(
    const u16* __restrict__ A, const u16* __restrict__ W1t, const u16* __restrict__ W2t,
    const float* __restrict__ b1, const float* __restrict__ b2,
    const float* __restrict__ accbuf, void* __restrict__ outp){
  __shared__ __align__(16) u16 As[6 * 64 * 64];    // 48 KB: A resident, 6 k-tiles
  __shared__ __align__(16) u16 ring[2][256 * 64];  // 2 x 32 KB: W1 panel k-tiles
  __shared__ __align__(16) u16 Hs[4 * 64 * 64];    // 32 KB: H chunk, 4 k-panels

  const int tid  = threadIdx.x;
  const int lane = tid & 63;
  const int wv   = tid >> 6;          // 0..7
  const int quad = lane >> 4;
  const int l16  = lane & 15;
  const int rsw  = l16 & 7;
  const size_t m0 = (size_t)blockIdx.x * 64;
  const int srow = lane >> 3;
  const int scol = ((lane & 7) ^ srow) * 8;
  const int uwm = (wv & 1) * 32;      // up-phase: H row half
  const int pan = wv >> 1;            // up-phase: H col panel (64 wide)
  const int dwn = wv * 48;            // down-phase: C col slice (disjoint W2 rows)

  // stage one W1 panel k-tile (256 rows x 64 k) into a ring buffer: 4 loads
  auto stage_up = [&](int hc, int kt, u16* buf){
#pragma unroll
    for (int i = 0; i < 4; ++i){
      int rg = i * 8 + wv;
      gload_lds16(W1t + ((size_t)hc + rg * 8 + srow) * 384 + kt * 64 + scol,
                  buf + rg * 512);
    }
  };

  // stage A once: 6 k-tiles x (8 rows x 64 k) segments
#pragma unroll
  for (int i = 0; i < 6; ++i)
    gload_lds16(A + (m0 + (size_t)(wv * 8 + srow)) * 384 + i * 64 + scol,
                As + (i * 8 + wv) * 512);
  stage_up(0, 0, ring[0]);   // prologue: U0 -> buf0

  f32x4 cacc[4][3];
  const f32x4 zero = {0.f, 0.f, 0.f, 0.f};
#pragma unroll
  for (int mt = 0; mt < 4; ++mt)
#pragma unroll
    for (int nt = 0; nt < 3; ++nt) cacc[mt][nt] = zero;

  for (int c = 0; c < NCH; ++c){
    const int hc = c * 256;
    f32x4 hacc[2][4];
#pragma unroll
    for (int mt = 0; mt < 2; ++mt)
#pragma unroll
      for (int nt = 0; nt < 4; ++nt) hacc[mt][nt] = zero;

    // ---- up: H[64][256] = A @ W1t[hc..hc+256]^T, pipelined W1 k-tiles ----
#pragma unroll
    for (int kt = 0; kt < 6; ++kt){
      if (kt < 5)           { stage_up(hc, kt + 1, ring[(kt + 1) & 1]); vm_wait<4>(); }
      else if (c + 1 < NCH) { stage_up(hc + 256, 0, ring[0]);           vm_wait<4>(); }
      else                  { vm_wait<0>(); }
      barrier_raw();
      const u16* buf = ring[kt & 1];
#pragma unroll
      for (int kk = 0; kk < 2; ++kk){
        short8 af[2], bfr[4];
#pragma unroll
        for (int mt = 0; mt < 2; ++mt)
          af[mt] = *(const short8*)(As + kt*4096 + (uwm + mt*16 + l16) * 64 + (((kk*4 + quad) ^ rsw) << 3));
#pragma unroll
        for (int nt = 0; nt < 4; ++nt)
          bfr[nt] = *(const short8*)(buf + (pan*64 + nt*16 + l16) * 64 + (((kk*4 + quad) ^ rsw) << 3));
#pragma unroll
        for (int mt = 0; mt < 2; ++mt)
#pragma unroll
          for (int nt = 0; nt < 4; ++nt)
            hacc[mt][nt] = __builtin_amdgcn_mfma_f32_16x16x32_bf16(af[mt], bfr[nt], hacc[mt][nt], 0, 0, 0);
      }
      barrier_raw();
    }

    // ---- gelu + bf16 -> Hs (swizzled to match down-phase af reads) -------
    // prior-chunk down reads are complete: every wave passed the up-loop
    // barriers above after consuming its reads.
#pragma unroll
    for (int nt = 0; nt < 4; ++nt){
      int pc = nt*16 + l16;
      float bv = b1[hc + pan*64 + pc];
      u16* hp = Hs + pan*4096;
#pragma unroll
      for (int mt = 0; mt < 2; ++mt){
#pragma unroll
        for (int r = 0; r < 4; ++r){
          int row = uwm + mt*16 + quad*4 + r;
          hp[row*64 + (((pc >> 3) ^ (row & 7)) << 3) + (pc & 7)] = f2bf(gelu_fast(hacc[mt][nt][r] + bv));
        }
      }
    }
    lgkm_wait0();
    barrier_raw();

    // ---- down: C += H @ W2t[:, hc..hc+256]^T; W2 direct to regs, ---------
    // 2-deep named register double-buffer, NO barriers, NO LDS staging.
    short8 wb[2][3];
#pragma unroll
    for (int nt = 0; nt < 3; ++nt)
      wb[0][nt] = *(const short8*)(W2t + (size_t)(dwn + nt*16 + l16) * HIDT + hc + quad*8);
#pragma unroll
    for (int s = 0; s < 8; ++s){          // s = dt*2 + kk over K=256
      if (s < 7){
        int off = ((s+1) >> 1) * 64 + (((s+1) & 1) * 4 + quad) * 8;
#pragma unroll
        for (int nt = 0; nt < 3; ++nt)
          wb[(s+1) & 1][nt] = *(const short8*)(W2t + (size_t)(dwn + nt*16 + l16) * HIDT + hc + off);
      }
      int dt = s >> 1, kk = s & 1;
      short8 af[4];
#pragma unroll
      for (int mt = 0; mt < 4; ++mt)
        af[mt] = *(const short8*)(Hs + dt*4096 + (mt*16 + l16) * 64 + (((kk*4 + quad) ^ rsw) << 3));
#pragma unroll
      for (int mt = 0; mt < 4; ++mt)
#pragma unroll
        for (int nt = 0; nt < 3; ++nt)
          cacc[mt][nt] = __builtin_amdgcn_mfma_f32_16x16x32_bf16(af[mt], wb[s & 1][nt], cacc[mt][nt], 0, 0, 0);
    }
  }

  // ---- epilogue: C/D mapping col = lane&15, row = quad*4 + reg ------------
#pragma unroll
  for (int nt = 0; nt < 3; ++nt){
    int col = dwn + nt*16 + l16;
    float bv = b2[col];
#pragma unroll
    for (int mt = 0; mt < 4; ++mt){
      size_t mbase = m0 + mt*16 + quad*4;
#pragma unroll
      for (int r = 0; r < 4; ++r){
        size_t off = (mbase + r) * DIM + col;
        float vv = cacc[mt][nt][r] + bv;
        if (EPI == E_BIAS) ((u16*)outp)[off] = f2bf(vv);
        else /* E_FINAL */ ((float*)outp)[off] = accbuf[off] + vv;
      }
    }
  }
}

extern "C" void kernel_launch(void* const* d_in, const int* in_sizes, int n_in,
                              void* d_out, int out_size, void* d_ws, size_t ws_size,
                              hipStream_t stream) {
  const int W11 = DIM * HID;   // 589824
  const float* x   = (const float*)d_in[0];
  const float* n1s = (const float*)d_in[1];
  const float* n1b = (const float*)d_in[2];
  const float* n2s = (const float*)d_in[3];
  const float* n2b = (const float*)d_in[4];
  const float* qw  = (const float*)d_in[5];
  const float* tw1 = (const float*)d_in[6] + 4 * W11;  // titan_w1[4]
  const float* tb1 = (const float*)d_in[7] + 4 * HID;  // titan_b1[4]
  const float* tw2 = (const float*)d_in[8] + 4 * W11;  // titan_w2[4]
  const float* tb2 = (const float*)d_in[9] + 4 * DIM;  // titan_b2[4]
  const float* ow  = (const float*)d_in[10];
  const float* ob  = (const float*)d_in[11];
  const float* cw1 = (const float*)d_in[12];
  const float* cb1 = (const float*)d_in[13];
  const float* cw2 = (const float*)d_in[14];
  const float* cb2 = (const float*)d_in[15];
  const int* Tp = (const int*)d_in[16];
  const int* Hp = (const int*)d_in[17];
  const int* Wp = (const int*)d_in[18];
  const int M = in_sizes[0] / DIM;   // 16384 tokens

  char* ws = (char*)d_ws;
  if (ws_size < 22611456u) return;
  u16*  y    = (u16*) (ws + 0);            // M x 384 bf16 (LN out, then t1, then LN2 out)
  u16*  qwT  = (u16*) (ws + 12582912);     // 384 x 384
  u16*  owT  = (u16*) (ws + 12877824);     // 384 x 384
  u16*  w1T  = (u16*) (ws + 13172736);     // 1536 x 384
  u16*  w2T  = (u16*) (ws + 14352384);     // 384 x 1536
  u16*  cw1T = (u16*) (ws + 15532032);     // 4608 x 384 (3 stacked)
  u16*  cw2T = (u16*) (ws + 19070976);     // 384 x 4608 (K-stacked)
  float* cb2s = (float*)(ws + 22609920);   // 384 f32
  u16*  qb   = (u16*)d_out;                // bf16 q scratch; later f32 x2/out

  // 1. transpose+convert weights to bf16 [N][K]
  transpose_kernel<384,384><<<dim3(12,12,2),256,0,stream>>>(
      qw, ow, qw, qw, qwT, owT, qwT, qwT, 384);
  transpose_kernel<384,1536><<<dim3(48,12,4),256,0,stream>>>(
      tw1, cw1, cw1 + W11, cw1 + 2*W11, w1T, cw1T, cw1T + W11, cw1T + 2*W11, 384);
  transpose_kernel<1536,384><<<dim3(12,48,1),256,0,stream>>>(
      tw2, tw2, tw2, tw2, w2T, w2T, w2T, w2T, 1536);
  transpose_kernel<1536,384><<<dim3(12,48,3),256,0,stream>>>(
      cw2, cw2 + W11, cw2 + 2*W11, cw2, cw2T, cw2T + 1536, cw2T + 3072, cw2T, 4608);
  bias3_kernel<<<1,384,0,stream>>>(cb2, cb2s);

  // 2. y = LN1(x)
  ln_kernel<<<M/4,256,0,stream>>>(x, n1s, n1b, y);
  // 3. q = y @ q_w   (bf16, into d_out)
  gemm_kernel<64,384,384,E_NONE><<<dim3(M/64,3),256,0,stream>>>(y, qwT, qb, nullptr, nullptr, nullptr);
  // 4. RoPE(q) in-place
  rope_kernel<<<(M*192)/256,256,0,stream>>>(qb, Tp, Hp, Wp, M);
  // 5+6. t1 = gelu(q @ w1 + b1) @ w2 + b2   (fused, q in d_out -> t1 in y)
  fused_mlp4_kernel<1536,6,E_BIAS><<<M/64,512,0,stream>>>(
      qb, w1T, w2T, tb1, tb2, nullptr, y);
  // 7. x2 = x + t1 @ out_w + out_b   (f32, into d_out)
  gemm_kernel<64,384,384,E_RES_F32><<<dim3(M/64,3),256,0,stream>>>(
      y, owT, nullptr, ob, x, (float*)d_out);
  // 8. y2 = LN2(x2)
  ln_kernel<<<M/4,256,0,stream>>>((const float*)d_out, n2s, n2b, y);
  // 9. cms: d_out = x2 + gelu(y @ cw1cat + cb1) @ cw2cat + cb2s   (one pass)
  fused_mlp4_kernel<4608,18,E_FINAL><<<M/64,512,0,stream>>>(
      y, cw1T, cw2T, cb1, cb2s, (const float*)d_out, d_out);
}